// Round 6
// baseline (387.970 us; speedup 1.0000x reference)
//
#include <hip/hip_runtime.h>
#include <hip/hip_bf16.h>
#include <math.h>

#define NN   100000
#define EE   200000
#define KK   4
#define DEG  8
#define FEAT 256
#define RANK 64
#define HID  512
#define OUTD 128
#define EPB  25000   // edges per permutation block = NN/KK

// num = DEG^(1/K) = 8^0.25 ; coef = num / (K-1)! = num/6
#define NUMF  1.6817928305074290861f
#define COEF  0.28029880508457151435f

typedef __attribute__((ext_vector_type(8))) short short8;
typedef __attribute__((ext_vector_type(4))) short short4v;
typedef __attribute__((ext_vector_type(2))) short short2v;
typedef __attribute__((ext_vector_type(4))) float float4v;

__device__ __forceinline__ short f2bf(float x) {
    union { float f; unsigned u; } v; v.f = x;
    unsigned r = v.u + 0x7fff + ((v.u >> 16) & 1);   // RNE
    return (short)(r >> 16);
}
__device__ __forceinline__ float bf2f(short u) {
    union { unsigned u; float f; } v;
    v.u = ((unsigned)(unsigned short)u) << 16;
    return v.f;
}
// fast tanh: 1 - 2/(e^{2y}+1); exact at +-inf, ~1ulp of v_exp_f32 elsewhere
__device__ __forceinline__ float fast_tanh(float y) {
    float ez = __expf(2.f * y);
    return 1.f - 2.f * __builtin_amdgcn_rcpf(ez + 1.f);
}

// ---------------------------------------------------------------------------
// Pack Wp/W1/W2/Wq (fp32 row-major [K x N]) into bf16 MFMA B-fragment order:
// tile (nt,kt) 32(k) x 16(n); lane l holds W[kt*32+(l>>4)*8+j][nt*16+(l&15)].
// ---------------------------------------------------------------------------
__global__ __launch_bounds__(256) void pack_w(
    const float* __restrict__ Wp, const float* __restrict__ W1,
    const float* __restrict__ W2, const float* __restrict__ Wq,
    short* __restrict__ bWp, short* __restrict__ bW1,
    short* __restrict__ bW2, short* __restrict__ bWq)
{
    int g = blockIdx.x * 256 + threadIdx.x;   // 108 blocks * 256 = (32+256+128+16)*64
    int tile = g >> 6, l = g & 63;
    int lm = l & 15, lq = l >> 4;
    const float* src; short* dst; int N, kt, nt, tl;
    if (tile < 32)       { tl = tile;        nt = tl >> 3; kt = tl & 7;  src = Wp; dst = bWp; N = RANK; }
    else if (tile < 288) { tl = tile - 32;   nt = tl >> 3; kt = tl & 7;  src = W1; dst = bW1; N = HID;  }
    else if (tile < 416) { tl = tile - 288;  nt = tl >> 4; kt = tl & 15; src = W2; dst = bW2; N = OUTD; }
    else                 { tl = tile - 416;  nt = tl >> 1; kt = tl & 1;  src = Wq; dst = bWq; N = OUTD; }
    short8 pk;
    #pragma unroll
    for (int j = 0; j < 8; ++j)
        pk[j] = f2bf(src[(size_t)(kt * 32 + lq * 8 + j) * N + nt * 16 + lm]);
    *reinterpret_cast<short8*>(dst + (size_t)(tl * 64 + l) * 8) = pk;
}

// ---------------------------------------------------------------------------
// Fused node network, v5: M-tile 32 -> 64 rows/block (STRUCTURAL ILP fix).
// r4 proved source-level load batching is a no-op (identical codegen, VGPR
// 56); the schedule only moves via structure. 64 rows/wave-group gives each
// wave 4 independent accumulator chains (rows lm+16q, q=0..3) instead of 2,
// doubles MFMA work per weight-load stream and per barrier, halves barriers
// per row. LDS 50KB -> 3 blocks/CU (12 waves/CU, same as measured r0).
// Tail: block 1562 has 32 valid rows; staging clamps, stores guard.
// ---------------------------------------------------------------------------
__global__ __launch_bounds__(256) void node_net_mfma(
    const float* __restrict__ emb,
    const short8* __restrict__ bWp, const float* __restrict__ bp,
    const short8* __restrict__ bW1, const float* __restrict__ b1,
    const short8* __restrict__ bW2, const float* __restrict__ b2,
    short* __restrict__ scaled_b, short* __restrict__ emb2_b)
{
    __shared__ short s_a[64][264];   // 64 x 256 bf16, row stride 528 B (33.8 KB)
    __shared__ short s_h[64][136];   // 64 x 128 bf16 chunk (17.4 KB)

    const int t = threadIdx.x;
    const int w = t >> 6, l = t & 63;
    const int lm = l & 15, lq = l >> 4;
    const int row0 = blockIdx.x * 64;

    for (int i = t; i < 64 * 32; i += 256) {
        int r = i >> 5, c8 = (i & 31) * 8;
        int srow = row0 + r; if (srow >= NN) srow = NN - 1;   // tail clamp (reads only)
        const float4* src = reinterpret_cast<const float4*>(emb + (size_t)srow * FEAT + c8);
        float4 v0 = src[0], v1 = src[1];
        short8 pk;
        pk[0] = f2bf(v0.x); pk[1] = f2bf(v0.y); pk[2] = f2bf(v0.z); pk[3] = f2bf(v0.w);
        pk[4] = f2bf(v1.x); pk[5] = f2bf(v1.y); pk[6] = f2bf(v1.z); pk[7] = f2bf(v1.w);
        *reinterpret_cast<short8*>(&s_a[r][c8]) = pk;
    }
    __syncthreads();

    // ---- stage p: scaled (4 independent chains) ----
    {
        float4v acc[4];
        #pragma unroll
        for (int q = 0; q < 4; ++q) acc[q] = (float4v){0.f, 0.f, 0.f, 0.f};
        #pragma unroll
        for (int kt = 0; kt < 8; ++kt) {
            short8 wv = bWp[(w * 8 + kt) * 64 + l];
            #pragma unroll
            for (int q = 0; q < 4; ++q) {
                short8 e = *reinterpret_cast<const short8*>(&s_a[q * 16 + lm][kt * 32 + lq * 8]);
                acc[q] = __builtin_amdgcn_mfma_f32_16x16x32_bf16(wv, e, acc[q], 0, 0, 0);
            }
        }
        const int cb = w * 16 + lq * 4;
        float4 bb = *reinterpret_cast<const float4*>(bp + cb);
        #pragma unroll
        for (int q = 0; q < 4; ++q) {
            const int row = row0 + q * 16 + lm;
            if (row < NN) {
                short4v o = { f2bf(NUMF * (acc[q][0] + bb.x)), f2bf(NUMF * (acc[q][1] + bb.y)),
                              f2bf(NUMF * (acc[q][2] + bb.z)), f2bf(NUMF * (acc[q][3] + bb.w)) };
                *reinterpret_cast<short4v*>(scaled_b + (size_t)row * RANK + cb) = o;
            }
        }
    }

    // ---- chunk-fused stage1/stage2 ----
    float4v eacc[4][2];
    #pragma unroll
    for (int q = 0; q < 4; ++q)
        #pragma unroll
        for (int n2 = 0; n2 < 2; ++n2)
            eacc[q][n2] = (float4v){0.f, 0.f, 0.f, 0.f};

    for (int cc = 0; cc < 4; ++cc) {
        #pragma unroll
        for (int nt2 = 0; nt2 < 2; ++nt2) {
            const int gnt = cc * 8 + w * 2 + nt2;
            float4v h[4];
            #pragma unroll
            for (int q = 0; q < 4; ++q) h[q] = (float4v){0.f, 0.f, 0.f, 0.f};
            #pragma unroll
            for (int kt = 0; kt < 8; ++kt) {
                short8 wv = bW1[(gnt * 8 + kt) * 64 + l];
                #pragma unroll
                for (int q = 0; q < 4; ++q) {
                    short8 e = *reinterpret_cast<const short8*>(&s_a[q * 16 + lm][kt * 32 + lq * 8]);
                    h[q] = __builtin_amdgcn_mfma_f32_16x16x32_bf16(wv, e, h[q], 0, 0, 0);
                }
            }
            const int col = w * 32 + nt2 * 16 + lq * 4;   // chunk-local
            float4 bb = *reinterpret_cast<const float4*>(b1 + cc * 128 + col);
            #pragma unroll
            for (int q = 0; q < 4; ++q) {
                short4v o = { f2bf(fmaxf(h[q][0] + bb.x, 0.f)), f2bf(fmaxf(h[q][1] + bb.y, 0.f)),
                              f2bf(fmaxf(h[q][2] + bb.z, 0.f)), f2bf(fmaxf(h[q][3] + bb.w, 0.f)) };
                *reinterpret_cast<short4v*>(&s_h[q * 16 + lm][col]) = o;
            }
        }
        __syncthreads();

        #pragma unroll
        for (int kt2 = 0; kt2 < 4; ++kt2) {
            short8 wv2[2];
            #pragma unroll
            for (int n2 = 0; n2 < 2; ++n2)
                wv2[n2] = bW2[((w * 2 + n2) * 16 + cc * 4 + kt2) * 64 + l];
            #pragma unroll
            for (int q = 0; q < 4; ++q) {
                short8 hh = *reinterpret_cast<const short8*>(&s_h[q * 16 + lm][kt2 * 32 + lq * 8]);
                #pragma unroll
                for (int n2 = 0; n2 < 2; ++n2)
                    eacc[q][n2] = __builtin_amdgcn_mfma_f32_16x16x32_bf16(wv2[n2], hh, eacc[q][n2], 0, 0, 0);
            }
        }
        __syncthreads();
    }

    #pragma unroll
    for (int n2 = 0; n2 < 2; ++n2) {
        const int col = w * 32 + n2 * 16 + lq * 4;
        float4 bb = *reinterpret_cast<const float4*>(b2 + col);
        #pragma unroll
        for (int q = 0; q < 4; ++q) {
            const int row = row0 + q * 16 + lm;
            if (row < NN) {
                short4v o = { f2bf(eacc[q][n2][0] + bb.x), f2bf(eacc[q][n2][1] + bb.y),
                              f2bf(eacc[q][n2][2] + bb.z), f2bf(eacc[q][n2][3] + bb.w) };
                *reinterpret_cast<short4v*>(emb2_b + (size_t)row * OUTD + col) = o;
            }
        }
    }
}

// ---------------------------------------------------------------------------
// Per-edge: edge2r = bf16( relu( sum_k emb2[node_k] ) ).
// ---------------------------------------------------------------------------
__global__ __launch_bounds__(256) void edge_sum(
    const short* __restrict__ emb2_b, const int* __restrict__ edge_nodes,
    short* __restrict__ edge2r)
{
    const int t = threadIdx.x;
    const int w = t >> 6, l = t & 63;
    const int c = 2 * l;
    const int e0 = blockIdx.x * 32 + w * 8;
    #pragma unroll
    for (int it = 0; it < 8; ++it) {
        const int e = e0 + it;
        const int4 nd = *reinterpret_cast<const int4*>(edge_nodes + (size_t)e * KK);
        short2v u0 = *reinterpret_cast<const short2v*>(emb2_b + (size_t)nd.x * OUTD + c);
        short2v u1 = *reinterpret_cast<const short2v*>(emb2_b + (size_t)nd.y * OUTD + c);
        short2v u2 = *reinterpret_cast<const short2v*>(emb2_b + (size_t)nd.z * OUTD + c);
        short2v u3 = *reinterpret_cast<const short2v*>(emb2_b + (size_t)nd.w * OUTD + c);
        float s0 = bf2f(u0[0]) + bf2f(u1[0]) + bf2f(u2[0]) + bf2f(u3[0]);
        float s1 = bf2f(u0[1]) + bf2f(u1[1]) + bf2f(u2[1]) + bf2f(u3[1]);
        short2v o = { f2bf(fmaxf(s0, 0.f)), f2bf(fmaxf(s1, 0.f)) };
        *reinterpret_cast<short2v*>(edge2r + (size_t)e * OUTD + c) = o;
    }
}

// ---------------------------------------------------------------------------
// Neighbor table: nbr[n*8+d] = {o0, o1, o2, e}. One writer per cell.
// ---------------------------------------------------------------------------
__global__ __launch_bounds__(256) void make_nbr(
    const int* __restrict__ edge_nodes, int4* __restrict__ nbr)
{
    int i = blockIdx.x * 256 + threadIdx.x;          // < EE*KK = 800000
    int e = i >> 2, k = i & 3;
    const int4 nd = *reinterpret_cast<const int4*>(edge_nodes + (size_t)e * KK);
    int n  = (k == 0) ? nd.x : (k == 1) ? nd.y : (k == 2) ? nd.z : nd.w;
    int o0 = (k == 0) ? nd.y : nd.x;
    int o1 = (k <= 1) ? nd.z : nd.y;
    int o2 = (k <= 2) ? nd.w : nd.z;
    int d = e / EPB;
    nbr[(size_t)n * 8 + d] = make_int4(o0, o1, o2, e);
}

// ---------------------------------------------------------------------------
// Per-node, v3 (r0 structure): 16 nodes/block. Gather phase (4 nodes/wave):
// tsum via fast tanh -> s_t bf16; edge2 sums -> s_s fp32. One swapped-operand
// MFMA (bWq frag x s_t frag) does all 16 node mat-vecs; lane=node C-layout.
// Gathers are L2/L3-resident (scaled_b 12.8MB, edge2r 51.2MB) — r3 showed
// reorganizing them into scatter+coalesced round-trips nets ~0.
// ---------------------------------------------------------------------------
__global__ __launch_bounds__(256, 4) void node_out(
    const short* __restrict__ scaled_b, const short* __restrict__ edge2r,
    const int4* __restrict__ nbr,
    const short8* __restrict__ bWq, const float* __restrict__ bq,
    float* __restrict__ out)
{
    __shared__ short s_t[16][72];    // tsum bf16; pad 64->72: frag rows 4 banks apart
    __shared__ float s_s[16][132];   // edge2 sums fp32; pad 128->132

    const int t = threadIdx.x;
    const int w = t >> 6, l = t & 63;
    const int lm = l & 15, lq = l >> 4;
    const int c = 2 * l;
    const int nbase = blockIdx.x * 16;

    #pragma unroll
    for (int j = 0; j < 4; ++j) {
        const int n = nbase + w * 4 + j;
        int4 nb[8];
        #pragma unroll
        for (int d = 0; d < 8; ++d) nb[d] = nbr[(size_t)n * 8 + d];

        float tsum = 0.f, s0 = 0.f, s1 = 0.f;
        #pragma unroll
        for (int d = 0; d < 8; ++d) {
            float g1 = bf2f(scaled_b[(size_t)nb[d].x * RANK + l]);
            float g2 = bf2f(scaled_b[(size_t)nb[d].y * RANK + l]);
            float g3 = bf2f(scaled_b[(size_t)nb[d].z * RANK + l]);
            short2v u = *reinterpret_cast<const short2v*>(edge2r + (size_t)nb[d].w * OUTD + c);
            tsum += fast_tanh(COEF * (g1 * (g2 * g3)));
            s0 += bf2f(u[0]);
            s1 += bf2f(u[1]);
        }
        s_t[w * 4 + j][l] = f2bf(tsum);
        *reinterpret_cast<float2*>(&s_s[w * 4 + j][c]) = make_float2(s0, s1);
    }
    __syncthreads();

    // MFMA mat-vec: Q^T = Wq^T @ T^T ; wave w owns out cols [w*32, +32)
    float4v acc0 = {0.f, 0.f, 0.f, 0.f}, acc1 = {0.f, 0.f, 0.f, 0.f};
    #pragma unroll
    for (int kt = 0; kt < 2; ++kt) {
        short8 tf = *reinterpret_cast<const short8*>(&s_t[lm][kt * 32 + lq * 8]);
        short8 w0 = bWq[((w * 2 + 0) * 2 + kt) * 64 + l];
        short8 w1 = bWq[((w * 2 + 1) * 2 + kt) * 64 + l];
        acc0 = __builtin_amdgcn_mfma_f32_16x16x32_bf16(w0, tf, acc0, 0, 0, 0);
        acc1 = __builtin_amdgcn_mfma_f32_16x16x32_bf16(w1, tf, acc1, 0, 0, 0);
    }
    #pragma unroll
    for (int n2 = 0; n2 < 2; ++n2) {
        float4v a = n2 ? acc1 : acc0;
        const int col = w * 32 + n2 * 16 + lq * 4;
        float4 sv = *reinterpret_cast<const float4*>(&s_s[lm][col]);
        float4 bb = *reinterpret_cast<const float4*>(bq + col);
        float4 o;
        o.x = fmaxf(fmaf(0.125f, a[0] + sv.x, bb.x), 0.f);
        o.y = fmaxf(fmaf(0.125f, a[1] + sv.y, bb.y), 0.f);
        o.z = fmaxf(fmaf(0.125f, a[2] + sv.z, bb.z), 0.f);
        o.w = fmaxf(fmaf(0.125f, a[3] + sv.w, bb.w), 0.f);
        *reinterpret_cast<float4*>(out + (size_t)(nbase + lm) * OUTD + col) = o;
    }
}

extern "C" void kernel_launch(void* const* d_in, const int* in_sizes, int n_in,
                              void* d_out, int out_size, void* d_ws, size_t ws_size,
                              hipStream_t stream)
{
    const float* emb = (const float*)d_in[0];
    const float* Wp  = (const float*)d_in[1];
    const float* bp  = (const float*)d_in[2];
    const float* Wq  = (const float*)d_in[3];
    const float* bq  = (const float*)d_in[4];
    const float* W1  = (const float*)d_in[5];
    const float* b1  = (const float*)d_in[6];
    const float* W2  = (const float*)d_in[7];
    const float* b2  = (const float*)d_in[8];
    const int* edge_nodes = (const int*)d_in[9];
    float* out = (float*)d_out;

    // workspace layout (r0); nbr ALIASES emb2_b (emb2_b dead after edge_sum).
    short* scaled_b = (short*)d_ws;                          // NN*64  bf16 = 12.8 MB
    short* emb2_b   = scaled_b + (size_t)NN * RANK;          // NN*128 bf16 = 25.6 MB
    short* edge2r   = emb2_b + (size_t)NN * OUTD;            // EE*128 bf16 = 51.2 MB
    short* bWp      = edge2r + (size_t)EE * OUTD;            // 32 KB
    short* bW1      = bWp + 256 * 64;                        // 256 KB
    short* bW2      = bW1 + 256 * 512;                       // 128 KB
    short* bWq      = bW2 + 512 * 128;                       // 16 KB
    int4*  nbr      = (int4*)emb2_b;                         // NN*8 int4 = 12.8 MB (alias)

    pack_w<<<108, 256, 0, stream>>>(Wp, W1, W2, Wq, bWp, bW1, bW2, bWq);
    node_net_mfma<<<(NN + 63) / 64, 256, 0, stream>>>(
        emb, (const short8*)bWp, bp, (const short8*)bW1, b1, (const short8*)bW2, b2,
        scaled_b, emb2_b);
    edge_sum<<<EE / 32, 256, 0, stream>>>(emb2_b, edge_nodes, edge2r);
    make_nbr<<<EE * KK / 256, 256, 0, stream>>>(edge_nodes, nbr);   // overwrites emb2_b
    node_out<<<NN / 16, 256, 0, stream>>>(scaled_b, edge2r, nbr, (const short8*)bWq, bq, out);
}

// Round 8
// 375.440 us; speedup vs baseline: 1.0334x; 1.0334x over previous
//
#include <hip/hip_runtime.h>
#include <hip/hip_bf16.h>
#include <math.h>

#define NN   100000
#define EE   200000
#define KK   4
#define DEG  8
#define FEAT 256
#define RANK 64
#define HID  512
#define OUTD 128
#define EPB  25000   // edges per permutation block = NN/KK

// num = DEG^(1/K) = 8^0.25 ; coef = num / (K-1)! = num/6
#define NUMF  1.6817928305074290861f
#define COEF  0.28029880508457151435f

typedef __attribute__((ext_vector_type(8))) short short8;
typedef __attribute__((ext_vector_type(4))) short short4v;
typedef __attribute__((ext_vector_type(2))) short short2v;
typedef __attribute__((ext_vector_type(4))) float float4v;
typedef __attribute__((ext_vector_type(4))) float f32x4;   // nt-capable 16B vector
typedef __attribute__((ext_vector_type(4))) int   i32x4;   // nt-capable 16B vector

__device__ __forceinline__ short f2bf(float x) {
    union { float f; unsigned u; } v; v.f = x;
    unsigned r = v.u + 0x7fff + ((v.u >> 16) & 1);   // RNE
    return (short)(r >> 16);
}
__device__ __forceinline__ float bf2f(short u) {
    union { unsigned u; float f; } v;
    v.u = ((unsigned)(unsigned short)u) << 16;
    return v.f;
}
// fast tanh: 1 - 2/(e^{2y}+1); exact at +-inf, ~1ulp of v_exp_f32 elsewhere
__device__ __forceinline__ float fast_tanh(float y) {
    float ez = __expf(2.f * y);
    return 1.f - 2.f * __builtin_amdgcn_rcpf(ez + 1.f);
}

// ---------------------------------------------------------------------------
// Pack Wp/W1/W2/Wq (fp32 row-major [K x N]) into bf16 MFMA B-fragment order:
// tile (nt,kt) 32(k) x 16(n); lane l holds W[kt*32+(l>>4)*8+j][nt*16+(l&15)].
// ---------------------------------------------------------------------------
__global__ __launch_bounds__(256) void pack_w(
    const float* __restrict__ Wp, const float* __restrict__ W1,
    const float* __restrict__ W2, const float* __restrict__ Wq,
    short* __restrict__ bWp, short* __restrict__ bW1,
    short* __restrict__ bW2, short* __restrict__ bWq)
{
    int g = blockIdx.x * 256 + threadIdx.x;   // 108 blocks * 256 = (32+256+128+16)*64
    int tile = g >> 6, l = g & 63;
    int lm = l & 15, lq = l >> 4;
    const float* src; short* dst; int N, kt, nt, tl;
    if (tile < 32)       { tl = tile;        nt = tl >> 3; kt = tl & 7;  src = Wp; dst = bWp; N = RANK; }
    else if (tile < 288) { tl = tile - 32;   nt = tl >> 3; kt = tl & 7;  src = W1; dst = bW1; N = HID;  }
    else if (tile < 416) { tl = tile - 288;  nt = tl >> 4; kt = tl & 15; src = W2; dst = bW2; N = OUTD; }
    else                 { tl = tile - 416;  nt = tl >> 1; kt = tl & 1;  src = Wq; dst = bWq; N = OUTD; }
    short8 pk;
    #pragma unroll
    for (int j = 0; j < 8; ++j)
        pk[j] = f2bf(src[(size_t)(kt * 32 + lq * 8 + j) * N + nt * 16 + lm]);
    *reinterpret_cast<short8*>(dst + (size_t)(tl * 64 + l) * 8) = pk;
}

// ---------------------------------------------------------------------------
// Fused node network (r0 structure, 32 rows/block — proven local optimum:
// r1 reg-hoist, r4 load-batching, r6 M=64 all neutral/regressed; throughput
// tracks resident waves). NEW: emb loads are NON-TEMPORAL — emb (102MB) is a
// zero-reuse stream that was evicting the gather intermediates from L3
// (evidence: FETCH_SIZE 54MB = half of emb re-fetched from HBM each iter),
// which made node_out's 512MB of gathers HBM-random-bound (~190us).
// ---------------------------------------------------------------------------
__global__ __launch_bounds__(256) void node_net_mfma(
    const float* __restrict__ emb,
    const short8* __restrict__ bWp, const float* __restrict__ bp,
    const short8* __restrict__ bW1, const float* __restrict__ b1,
    const short8* __restrict__ bW2, const float* __restrict__ b2,
    short* __restrict__ scaled_b, short* __restrict__ emb2_b)
{
    __shared__ short s_a[32][264];   // 32 x 256 bf16, row stride 528 B
    __shared__ short s_h[32][136];   // 32 x 128 bf16 chunk

    const int t = threadIdx.x;
    const int w = t >> 6, l = t & 63;
    const int lm = l & 15, lq = l >> 4;
    const int row0 = blockIdx.x * 32;

    for (int i = t; i < 32 * 32; i += 256) {
        int r = i >> 5, c8 = (i & 31) * 8;
        const f32x4* src = reinterpret_cast<const f32x4*>(emb + (size_t)(row0 + r) * FEAT + c8);
        f32x4 v0 = __builtin_nontemporal_load(src);        // nt: keep L3 for intermediates
        f32x4 v1 = __builtin_nontemporal_load(src + 1);
        short8 pk;
        pk[0] = f2bf(v0[0]); pk[1] = f2bf(v0[1]); pk[2] = f2bf(v0[2]); pk[3] = f2bf(v0[3]);
        pk[4] = f2bf(v1[0]); pk[5] = f2bf(v1[1]); pk[6] = f2bf(v1[2]); pk[7] = f2bf(v1[3]);
        *reinterpret_cast<short8*>(&s_a[r][c8]) = pk;
    }
    __syncthreads();

    // ---- stage p: scaled ----
    {
        float4v acc0 = {0.f, 0.f, 0.f, 0.f}, acc1 = {0.f, 0.f, 0.f, 0.f};
        #pragma unroll
        for (int kt = 0; kt < 8; ++kt) {
            short8 e0 = *reinterpret_cast<const short8*>(&s_a[lm][kt * 32 + lq * 8]);
            short8 e1 = *reinterpret_cast<const short8*>(&s_a[16 + lm][kt * 32 + lq * 8]);
            short8 wv = bWp[(w * 8 + kt) * 64 + l];
            acc0 = __builtin_amdgcn_mfma_f32_16x16x32_bf16(wv, e0, acc0, 0, 0, 0);
            acc1 = __builtin_amdgcn_mfma_f32_16x16x32_bf16(wv, e1, acc1, 0, 0, 0);
        }
        const int cb = w * 16 + lq * 4;
        float4 bb = *reinterpret_cast<const float4*>(bp + cb);
        short4v o0 = { f2bf(NUMF * (acc0[0] + bb.x)), f2bf(NUMF * (acc0[1] + bb.y)),
                       f2bf(NUMF * (acc0[2] + bb.z)), f2bf(NUMF * (acc0[3] + bb.w)) };
        short4v o1 = { f2bf(NUMF * (acc1[0] + bb.x)), f2bf(NUMF * (acc1[1] + bb.y)),
                       f2bf(NUMF * (acc1[2] + bb.z)), f2bf(NUMF * (acc1[3] + bb.w)) };
        *reinterpret_cast<short4v*>(scaled_b + (size_t)(row0 + lm) * RANK + cb)      = o0;
        *reinterpret_cast<short4v*>(scaled_b + (size_t)(row0 + 16 + lm) * RANK + cb) = o1;
    }

    // ---- chunk-fused stage1/stage2 ----
    float4v eacc[2][2];
    #pragma unroll
    for (int mt = 0; mt < 2; ++mt)
        #pragma unroll
        for (int n2 = 0; n2 < 2; ++n2)
            eacc[mt][n2] = (float4v){0.f, 0.f, 0.f, 0.f};

    for (int cc = 0; cc < 4; ++cc) {
        #pragma unroll
        for (int nt2 = 0; nt2 < 2; ++nt2) {
            float4v h0 = {0.f, 0.f, 0.f, 0.f}, h1 = {0.f, 0.f, 0.f, 0.f};
            const int gnt = cc * 8 + w * 2 + nt2;
            #pragma unroll
            for (int kt = 0; kt < 8; ++kt) {
                short8 e0 = *reinterpret_cast<const short8*>(&s_a[lm][kt * 32 + lq * 8]);
                short8 e1 = *reinterpret_cast<const short8*>(&s_a[16 + lm][kt * 32 + lq * 8]);
                short8 wv = bW1[(gnt * 8 + kt) * 64 + l];
                h0 = __builtin_amdgcn_mfma_f32_16x16x32_bf16(wv, e0, h0, 0, 0, 0);
                h1 = __builtin_amdgcn_mfma_f32_16x16x32_bf16(wv, e1, h1, 0, 0, 0);
            }
            const int col  = w * 32 + nt2 * 16 + lq * 4;   // chunk-local
            float4 bb = *reinterpret_cast<const float4*>(b1 + cc * 128 + col);
            short4v o0 = { f2bf(fmaxf(h0[0] + bb.x, 0.f)), f2bf(fmaxf(h0[1] + bb.y, 0.f)),
                           f2bf(fmaxf(h0[2] + bb.z, 0.f)), f2bf(fmaxf(h0[3] + bb.w, 0.f)) };
            short4v o1 = { f2bf(fmaxf(h1[0] + bb.x, 0.f)), f2bf(fmaxf(h1[1] + bb.y, 0.f)),
                           f2bf(fmaxf(h1[2] + bb.z, 0.f)), f2bf(fmaxf(h1[3] + bb.w, 0.f)) };
            *reinterpret_cast<short4v*>(&s_h[lm][col])      = o0;
            *reinterpret_cast<short4v*>(&s_h[16 + lm][col]) = o1;
        }
        __syncthreads();

        #pragma unroll
        for (int kt2 = 0; kt2 < 4; ++kt2) {
            short8 hh0 = *reinterpret_cast<const short8*>(&s_h[lm][kt2 * 32 + lq * 8]);
            short8 hh1 = *reinterpret_cast<const short8*>(&s_h[16 + lm][kt2 * 32 + lq * 8]);
            const int gk = cc * 4 + kt2;
            #pragma unroll
            for (int n2 = 0; n2 < 2; ++n2) {
                short8 wv = bW2[((w * 2 + n2) * 16 + gk) * 64 + l];
                eacc[0][n2] = __builtin_amdgcn_mfma_f32_16x16x32_bf16(wv, hh0, eacc[0][n2], 0, 0, 0);
                eacc[1][n2] = __builtin_amdgcn_mfma_f32_16x16x32_bf16(wv, hh1, eacc[1][n2], 0, 0, 0);
            }
        }
        __syncthreads();
    }

    #pragma unroll
    for (int n2 = 0; n2 < 2; ++n2) {
        const int col = w * 32 + n2 * 16 + lq * 4;
        float4 bb = *reinterpret_cast<const float4*>(b2 + col);
        #pragma unroll
        for (int mt = 0; mt < 2; ++mt) {
            short4v o = { f2bf(eacc[mt][n2][0] + bb.x), f2bf(eacc[mt][n2][1] + bb.y),
                          f2bf(eacc[mt][n2][2] + bb.z), f2bf(eacc[mt][n2][3] + bb.w) };
            *reinterpret_cast<short4v*>(emb2_b + (size_t)(row0 + mt * 16 + lm) * OUTD + col) = o;
        }
    }
}

// ---------------------------------------------------------------------------
// Per-edge: edge2r = bf16( relu( sum_k emb2[node_k] ) ).
// emb2_b rows have 8x reuse across edges -> keep cached (no nt).
// ---------------------------------------------------------------------------
__global__ __launch_bounds__(256) void edge_sum(
    const short* __restrict__ emb2_b, const int* __restrict__ edge_nodes,
    short* __restrict__ edge2r)
{
    const int t = threadIdx.x;
    const int w = t >> 6, l = t & 63;
    const int c = 2 * l;
    const int e0 = blockIdx.x * 32 + w * 8;
    #pragma unroll
    for (int it = 0; it < 8; ++it) {
        const int e = e0 + it;
        const int4 nd = *reinterpret_cast<const int4*>(edge_nodes + (size_t)e * KK);
        short2v u0 = *reinterpret_cast<const short2v*>(emb2_b + (size_t)nd.x * OUTD + c);
        short2v u1 = *reinterpret_cast<const short2v*>(emb2_b + (size_t)nd.y * OUTD + c);
        short2v u2 = *reinterpret_cast<const short2v*>(emb2_b + (size_t)nd.z * OUTD + c);
        short2v u3 = *reinterpret_cast<const short2v*>(emb2_b + (size_t)nd.w * OUTD + c);
        float s0 = bf2f(u0[0]) + bf2f(u1[0]) + bf2f(u2[0]) + bf2f(u3[0]);
        float s1 = bf2f(u0[1]) + bf2f(u1[1]) + bf2f(u2[1]) + bf2f(u3[1]);
        short2v o = { f2bf(fmaxf(s0, 0.f)), f2bf(fmaxf(s1, 0.f)) };
        *reinterpret_cast<short2v*>(edge2r + (size_t)e * OUTD + c) = o;
    }
}

// ---------------------------------------------------------------------------
// Neighbor table: nbr[n*8+d] = {o0, o1, o2, e}. One writer per cell.
// Written once, read once (coalesced) -> non-temporal both sides, keeps
// another 12.8MB of L3 free for the high-reuse gather targets.
// ---------------------------------------------------------------------------
__global__ __launch_bounds__(256) void make_nbr(
    const int* __restrict__ edge_nodes, int* __restrict__ nbr)
{
    int i = blockIdx.x * 256 + threadIdx.x;          // < EE*KK = 800000
    int e = i >> 2, k = i & 3;
    const int4 nd = *reinterpret_cast<const int4*>(edge_nodes + (size_t)e * KK);
    int n  = (k == 0) ? nd.x : (k == 1) ? nd.y : (k == 2) ? nd.z : nd.w;
    int o0 = (k == 0) ? nd.y : nd.x;
    int o1 = (k <= 1) ? nd.z : nd.y;
    int o2 = (k <= 2) ? nd.w : nd.z;
    int d = e / EPB;
    i32x4 val = { o0, o1, o2, e };
    __builtin_nontemporal_store(val, reinterpret_cast<i32x4*>(nbr + ((size_t)n * 8 + d) * 4));
}

// ---------------------------------------------------------------------------
// Per-node (r0 structure): 16 nodes/block, 4 nodes/wave gather phase, then
// one swapped-operand Wq MFMA (lane=node C-layout) + fused epilogue.
// scaled_b rows: 24x reuse; edge2r rows: 4x reuse -> cached loads.
// nbr: read-once -> nt load. out: write-once -> nt store (don't evict
// edge2r mid-kernel with our own output stream).
// ---------------------------------------------------------------------------
__global__ __launch_bounds__(256, 4) void node_out(
    const short* __restrict__ scaled_b, const short* __restrict__ edge2r,
    const int* __restrict__ nbr,
    const short8* __restrict__ bWq, const float* __restrict__ bq,
    float* __restrict__ out)
{
    __shared__ short s_t[16][72];    // tsum bf16; pad 64->72: frag rows 4 banks apart
    __shared__ float s_s[16][132];   // edge2 sums fp32; pad 128->132

    const int t = threadIdx.x;
    const int w = t >> 6, l = t & 63;
    const int lm = l & 15, lq = l >> 4;
    const int c = 2 * l;
    const int nbase = blockIdx.x * 16;

    #pragma unroll
    for (int j = 0; j < 4; ++j) {
        const int n = nbase + w * 4 + j;
        i32x4 nb[8];
        #pragma unroll
        for (int d = 0; d < 8; ++d)
            nb[d] = __builtin_nontemporal_load(
                reinterpret_cast<const i32x4*>(nbr + ((size_t)n * 8 + d) * 4));

        float tsum = 0.f, s0 = 0.f, s1 = 0.f;
        #pragma unroll
        for (int d = 0; d < 8; ++d) {
            float g1 = bf2f(scaled_b[(size_t)nb[d][0] * RANK + l]);
            float g2 = bf2f(scaled_b[(size_t)nb[d][1] * RANK + l]);
            float g3 = bf2f(scaled_b[(size_t)nb[d][2] * RANK + l]);
            short2v u = *reinterpret_cast<const short2v*>(edge2r + (size_t)nb[d][3] * OUTD + c);
            tsum += fast_tanh(COEF * (g1 * (g2 * g3)));
            s0 += bf2f(u[0]);
            s1 += bf2f(u[1]);
        }
        s_t[w * 4 + j][l] = f2bf(tsum);
        *reinterpret_cast<float2*>(&s_s[w * 4 + j][c]) = make_float2(s0, s1);
    }
    __syncthreads();

    // MFMA mat-vec: Q^T = Wq^T @ T^T ; wave w owns out cols [w*32, +32)
    float4v acc0 = {0.f, 0.f, 0.f, 0.f}, acc1 = {0.f, 0.f, 0.f, 0.f};
    #pragma unroll
    for (int kt = 0; kt < 2; ++kt) {
        short8 tf = *reinterpret_cast<const short8*>(&s_t[lm][kt * 32 + lq * 8]);
        short8 w0 = bWq[((w * 2 + 0) * 2 + kt) * 64 + l];
        short8 w1 = bWq[((w * 2 + 1) * 2 + kt) * 64 + l];
        acc0 = __builtin_amdgcn_mfma_f32_16x16x32_bf16(w0, tf, acc0, 0, 0, 0);
        acc1 = __builtin_amdgcn_mfma_f32_16x16x32_bf16(w1, tf, acc1, 0, 0, 0);
    }
    #pragma unroll
    for (int n2 = 0; n2 < 2; ++n2) {
        float4v a = n2 ? acc1 : acc0;
        const int col = w * 32 + n2 * 16 + lq * 4;
        float4 sv = *reinterpret_cast<const float4*>(&s_s[lm][col]);
        float4 bb = *reinterpret_cast<const float4*>(bq + col);
        f32x4 o;
        o[0] = fmaxf(fmaf(0.125f, a[0] + sv.x, bb.x), 0.f);
        o[1] = fmaxf(fmaf(0.125f, a[1] + sv.y, bb.y), 0.f);
        o[2] = fmaxf(fmaf(0.125f, a[2] + sv.z, bb.z), 0.f);
        o[3] = fmaxf(fmaf(0.125f, a[3] + sv.w, bb.w), 0.f);
        __builtin_nontemporal_store(o, reinterpret_cast<f32x4*>(out + (size_t)(nbase + lm) * OUTD + col));
    }
}

extern "C" void kernel_launch(void* const* d_in, const int* in_sizes, int n_in,
                              void* d_out, int out_size, void* d_ws, size_t ws_size,
                              hipStream_t stream)
{
    const float* emb = (const float*)d_in[0];
    const float* Wp  = (const float*)d_in[1];
    const float* bp  = (const float*)d_in[2];
    const float* Wq  = (const float*)d_in[3];
    const float* bq  = (const float*)d_in[4];
    const float* W1  = (const float*)d_in[5];
    const float* b1  = (const float*)d_in[6];
    const float* W2  = (const float*)d_in[7];
    const float* b2  = (const float*)d_in[8];
    const int* edge_nodes = (const int*)d_in[9];
    float* out = (float*)d_out;

    // workspace layout (r0); nbr ALIASES emb2_b (emb2_b dead after edge_sum).
    short* scaled_b = (short*)d_ws;                          // NN*64  bf16 = 12.8 MB
    short* emb2_b   = scaled_b + (size_t)NN * RANK;          // NN*128 bf16 = 25.6 MB
    short* edge2r   = emb2_b + (size_t)NN * OUTD;            // EE*128 bf16 = 51.2 MB
    short* bWp      = edge2r + (size_t)EE * OUTD;            // 32 KB
    short* bW1      = bWp + 256 * 64;                        // 256 KB
    short* bW2      = bW1 + 256 * 512;                       // 128 KB
    short* bWq      = bW2 + 512 * 128;                       // 16 KB
    int*   nbr      = (int*)emb2_b;                          // NN*8 int4 = 12.8 MB (alias)

    pack_w<<<108, 256, 0, stream>>>(Wp, W1, W2, Wq, bWp, bW1, bW2, bWq);
    node_net_mfma<<<NN / 32, 256, 0, stream>>>(
        emb, (const short8*)bWp, bp, (const short8*)bW1, b1, (const short8*)bW2, b2,
        scaled_b, emb2_b);
    edge_sum<<<EE / 32, 256, 0, stream>>>(emb2_b, edge_nodes, edge2r);
    make_nbr<<<EE * KK / 256, 256, 0, stream>>>(edge_nodes, nbr);   // overwrites emb2_b
    node_out<<<NN / 16, 256, 0, stream>>>(scaled_b, edge2r, nbr, (const short8*)bWq, bq, out);
}

// Round 9
// 352.835 us; speedup vs baseline: 1.0996x; 1.0641x over previous
//
#include <hip/hip_runtime.h>
#include <hip/hip_bf16.h>
#include <math.h>

#define NN   100000
#define EE   200000
#define KK   4
#define DEG  8
#define FEAT 256
#define RANK 64
#define HID  512
#define OUTD 128
#define EPB  25000   // edges per permutation block = NN/KK

// num = DEG^(1/K) = 8^0.25 ; coef = num / (K-1)! = num/6
#define NUMF  1.6817928305074290861f
#define COEF  0.28029880508457151435f

typedef __attribute__((ext_vector_type(8))) short short8;
typedef __attribute__((ext_vector_type(4))) short short4v;
typedef __attribute__((ext_vector_type(2))) short short2v;
typedef __attribute__((ext_vector_type(4))) float float4v;
typedef __attribute__((ext_vector_type(4))) float f32x4;   // nt-capable 16B vector

__device__ __forceinline__ short f2bf(float x) {
    union { float f; unsigned u; } v; v.f = x;
    unsigned r = v.u + 0x7fff + ((v.u >> 16) & 1);   // RNE
    return (short)(r >> 16);
}
__device__ __forceinline__ float bf2f(short u) {
    union { unsigned u; float f; } v;
    v.u = ((unsigned)(unsigned short)u) << 16;
    return v.f;
}
// fast tanh: 1 - 2/(e^{2y}+1); exact at +-inf, ~1ulp of v_exp_f32 elsewhere
__device__ __forceinline__ float fast_tanh(float y) {
    float ez = __expf(2.f * y);
    return 1.f - 2.f * __builtin_amdgcn_rcpf(ez + 1.f);
}

// ---------------------------------------------------------------------------
// Pack Wp/W1/W2/Wq (fp32 row-major [K x N]) into bf16 MFMA B-fragment order:
// tile (nt,kt) 32(k) x 16(n); lane l holds W[kt*32+(l>>4)*8+j][nt*16+(l&15)].
// ---------------------------------------------------------------------------
__global__ __launch_bounds__(256) void pack_w(
    const float* __restrict__ Wp, const float* __restrict__ W1,
    const float* __restrict__ W2, const float* __restrict__ Wq,
    short* __restrict__ bWp, short* __restrict__ bW1,
    short* __restrict__ bW2, short* __restrict__ bWq)
{
    int g = blockIdx.x * 256 + threadIdx.x;   // 108 blocks * 256 = (32+256+128+16)*64
    int tile = g >> 6, l = g & 63;
    int lm = l & 15, lq = l >> 4;
    const float* src; short* dst; int N, kt, nt, tl;
    if (tile < 32)       { tl = tile;        nt = tl >> 3; kt = tl & 7;  src = Wp; dst = bWp; N = RANK; }
    else if (tile < 288) { tl = tile - 32;   nt = tl >> 3; kt = tl & 7;  src = W1; dst = bW1; N = HID;  }
    else if (tile < 416) { tl = tile - 288;  nt = tl >> 4; kt = tl & 15; src = W2; dst = bW2; N = OUTD; }
    else                 { tl = tile - 416;  nt = tl >> 1; kt = tl & 1;  src = Wq; dst = bWq; N = OUTD; }
    short8 pk;
    #pragma unroll
    for (int j = 0; j < 8; ++j)
        pk[j] = f2bf(src[(size_t)(kt * 32 + lq * 8 + j) * N + nt * 16 + lm]);
    *reinterpret_cast<short8*>(dst + (size_t)(tl * 64 + l) * 8) = pk;
}

// ---------------------------------------------------------------------------
// Fused node network (r0 structure, 32 rows/block — proven local optimum).
// emb loads NON-TEMPORAL (r8: -8.5us, FETCH 54->51.8MB — emb is a zero-reuse
// 102MB stream; nt keeps L3 for the high-reuse gather intermediates).
// ---------------------------------------------------------------------------
__global__ __launch_bounds__(256) void node_net_mfma(
    const float* __restrict__ emb,
    const short8* __restrict__ bWp, const float* __restrict__ bp,
    const short8* __restrict__ bW1, const float* __restrict__ b1,
    const short8* __restrict__ bW2, const float* __restrict__ b2,
    short* __restrict__ scaled_b, short* __restrict__ emb2_b)
{
    __shared__ short s_a[32][264];   // 32 x 256 bf16, row stride 528 B
    __shared__ short s_h[32][136];   // 32 x 128 bf16 chunk

    const int t = threadIdx.x;
    const int w = t >> 6, l = t & 63;
    const int lm = l & 15, lq = l >> 4;
    const int row0 = blockIdx.x * 32;

    for (int i = t; i < 32 * 32; i += 256) {
        int r = i >> 5, c8 = (i & 31) * 8;
        const f32x4* src = reinterpret_cast<const f32x4*>(emb + (size_t)(row0 + r) * FEAT + c8);
        f32x4 v0 = __builtin_nontemporal_load(src);        // nt: keep L3 for intermediates
        f32x4 v1 = __builtin_nontemporal_load(src + 1);
        short8 pk;
        pk[0] = f2bf(v0[0]); pk[1] = f2bf(v0[1]); pk[2] = f2bf(v0[2]); pk[3] = f2bf(v0[3]);
        pk[4] = f2bf(v1[0]); pk[5] = f2bf(v1[1]); pk[6] = f2bf(v1[2]); pk[7] = f2bf(v1[3]);
        *reinterpret_cast<short8*>(&s_a[r][c8]) = pk;
    }
    __syncthreads();

    // ---- stage p: scaled ----
    {
        float4v acc0 = {0.f, 0.f, 0.f, 0.f}, acc1 = {0.f, 0.f, 0.f, 0.f};
        #pragma unroll
        for (int kt = 0; kt < 8; ++kt) {
            short8 e0 = *reinterpret_cast<const short8*>(&s_a[lm][kt * 32 + lq * 8]);
            short8 e1 = *reinterpret_cast<const short8*>(&s_a[16 + lm][kt * 32 + lq * 8]);
            short8 wv = bWp[(w * 8 + kt) * 64 + l];
            acc0 = __builtin_amdgcn_mfma_f32_16x16x32_bf16(wv, e0, acc0, 0, 0, 0);
            acc1 = __builtin_amdgcn_mfma_f32_16x16x32_bf16(wv, e1, acc1, 0, 0, 0);
        }
        const int cb = w * 16 + lq * 4;
        float4 bb = *reinterpret_cast<const float4*>(bp + cb);
        short4v o0 = { f2bf(NUMF * (acc0[0] + bb.x)), f2bf(NUMF * (acc0[1] + bb.y)),
                       f2bf(NUMF * (acc0[2] + bb.z)), f2bf(NUMF * (acc0[3] + bb.w)) };
        short4v o1 = { f2bf(NUMF * (acc1[0] + bb.x)), f2bf(NUMF * (acc1[1] + bb.y)),
                       f2bf(NUMF * (acc1[2] + bb.z)), f2bf(NUMF * (acc1[3] + bb.w)) };
        *reinterpret_cast<short4v*>(scaled_b + (size_t)(row0 + lm) * RANK + cb)      = o0;
        *reinterpret_cast<short4v*>(scaled_b + (size_t)(row0 + 16 + lm) * RANK + cb) = o1;
    }

    // ---- chunk-fused stage1/stage2 ----
    float4v eacc[2][2];
    #pragma unroll
    for (int mt = 0; mt < 2; ++mt)
        #pragma unroll
        for (int n2 = 0; n2 < 2; ++n2)
            eacc[mt][n2] = (float4v){0.f, 0.f, 0.f, 0.f};

    for (int cc = 0; cc < 4; ++cc) {
        #pragma unroll
        for (int nt2 = 0; nt2 < 2; ++nt2) {
            float4v h0 = {0.f, 0.f, 0.f, 0.f}, h1 = {0.f, 0.f, 0.f, 0.f};
            const int gnt = cc * 8 + w * 2 + nt2;
            #pragma unroll
            for (int kt = 0; kt < 8; ++kt) {
                short8 e0 = *reinterpret_cast<const short8*>(&s_a[lm][kt * 32 + lq * 8]);
                short8 e1 = *reinterpret_cast<const short8*>(&s_a[16 + lm][kt * 32 + lq * 8]);
                short8 wv = bW1[(gnt * 8 + kt) * 64 + l];
                h0 = __builtin_amdgcn_mfma_f32_16x16x32_bf16(wv, e0, h0, 0, 0, 0);
                h1 = __builtin_amdgcn_mfma_f32_16x16x32_bf16(wv, e1, h1, 0, 0, 0);
            }
            const int col  = w * 32 + nt2 * 16 + lq * 4;   // chunk-local
            float4 bb = *reinterpret_cast<const float4*>(b1 + cc * 128 + col);
            short4v o0 = { f2bf(fmaxf(h0[0] + bb.x, 0.f)), f2bf(fmaxf(h0[1] + bb.y, 0.f)),
                           f2bf(fmaxf(h0[2] + bb.z, 0.f)), f2bf(fmaxf(h0[3] + bb.w, 0.f)) };
            short4v o1 = { f2bf(fmaxf(h1[0] + bb.x, 0.f)), f2bf(fmaxf(h1[1] + bb.y, 0.f)),
                           f2bf(fmaxf(h1[2] + bb.z, 0.f)), f2bf(fmaxf(h1[3] + bb.w, 0.f)) };
            *reinterpret_cast<short4v*>(&s_h[lm][col])      = o0;
            *reinterpret_cast<short4v*>(&s_h[16 + lm][col]) = o1;
        }
        __syncthreads();

        #pragma unroll
        for (int kt2 = 0; kt2 < 4; ++kt2) {
            short8 hh0 = *reinterpret_cast<const short8*>(&s_h[lm][kt2 * 32 + lq * 8]);
            short8 hh1 = *reinterpret_cast<const short8*>(&s_h[16 + lm][kt2 * 32 + lq * 8]);
            const int gk = cc * 4 + kt2;
            #pragma unroll
            for (int n2 = 0; n2 < 2; ++n2) {
                short8 wv = bW2[((w * 2 + n2) * 16 + gk) * 64 + l];
                eacc[0][n2] = __builtin_amdgcn_mfma_f32_16x16x32_bf16(wv, hh0, eacc[0][n2], 0, 0, 0);
                eacc[1][n2] = __builtin_amdgcn_mfma_f32_16x16x32_bf16(wv, hh1, eacc[1][n2], 0, 0, 0);
            }
        }
        __syncthreads();
    }

    #pragma unroll
    for (int n2 = 0; n2 < 2; ++n2) {
        const int col = w * 32 + n2 * 16 + lq * 4;
        float4 bb = *reinterpret_cast<const float4*>(b2 + col);
        #pragma unroll
        for (int mt = 0; mt < 2; ++mt) {
            short4v o = { f2bf(eacc[mt][n2][0] + bb.x), f2bf(eacc[mt][n2][1] + bb.y),
                          f2bf(eacc[mt][n2][2] + bb.z), f2bf(eacc[mt][n2][3] + bb.w) };
            *reinterpret_cast<short4v*>(emb2_b + (size_t)(row0 + mt * 16 + lm) * OUTD + col) = o;
        }
    }
}

// ---------------------------------------------------------------------------
// Per-edge: edge2r = bf16( relu( sum_k emb2[node_k] ) ).
// emb2_b rows have 8x reuse across edges -> keep cached (no nt).
// ---------------------------------------------------------------------------
__global__ __launch_bounds__(256) void edge_sum(
    const short* __restrict__ emb2_b, const int* __restrict__ edge_nodes,
    short* __restrict__ edge2r)
{
    const int t = threadIdx.x;
    const int w = t >> 6, l = t & 63;
    const int c = 2 * l;
    const int e0 = blockIdx.x * 32 + w * 8;
    #pragma unroll
    for (int it = 0; it < 8; ++it) {
        const int e = e0 + it;
        const int4 nd = *reinterpret_cast<const int4*>(edge_nodes + (size_t)e * KK);
        short2v u0 = *reinterpret_cast<const short2v*>(emb2_b + (size_t)nd.x * OUTD + c);
        short2v u1 = *reinterpret_cast<const short2v*>(emb2_b + (size_t)nd.y * OUTD + c);
        short2v u2 = *reinterpret_cast<const short2v*>(emb2_b + (size_t)nd.z * OUTD + c);
        short2v u3 = *reinterpret_cast<const short2v*>(emb2_b + (size_t)nd.w * OUTD + c);
        float s0 = bf2f(u0[0]) + bf2f(u1[0]) + bf2f(u2[0]) + bf2f(u3[0]);
        float s1 = bf2f(u0[1]) + bf2f(u1[1]) + bf2f(u2[1]) + bf2f(u3[1]);
        short2v o = { f2bf(fmaxf(s0, 0.f)), f2bf(fmaxf(s1, 0.f)) };
        *reinterpret_cast<short2v*>(edge2r + (size_t)e * OUTD + c) = o;
    }
}

// ---------------------------------------------------------------------------
// Neighbor table: nbr[n*8+d] = {o0, o1, o2, e}. One writer per cell.
// CACHED store/load (r8 lesson: nt on this table put a ~900cyc HBM load at
// the HEAD of node_out's gather dependency chain, +29us. nt is for streams
// nobody waits on; never nt a load that feeds addresses.)
// ---------------------------------------------------------------------------
__global__ __launch_bounds__(256) void make_nbr(
    const int* __restrict__ edge_nodes, int4* __restrict__ nbr)
{
    int i = blockIdx.x * 256 + threadIdx.x;          // < EE*KK = 800000
    int e = i >> 2, k = i & 3;
    const int4 nd = *reinterpret_cast<const int4*>(edge_nodes + (size_t)e * KK);
    int n  = (k == 0) ? nd.x : (k == 1) ? nd.y : (k == 2) ? nd.z : nd.w;
    int o0 = (k == 0) ? nd.y : nd.x;
    int o1 = (k <= 1) ? nd.z : nd.y;
    int o2 = (k <= 2) ? nd.w : nd.z;
    int d = e / EPB;
    nbr[(size_t)n * 8 + d] = make_int4(o0, o1, o2, e);
}

// ---------------------------------------------------------------------------
// Per-node (r0 structure): 16 nodes/block, 4 nodes/wave gather phase, then
// one swapped-operand Wq MFMA (lane=node C-layout) + fused epilogue.
// scaled_b/edge2r/nbr: cached (high reuse / address-feeding). out: nt store
// (write-once stream; don't evict edge2r mid-kernel with our own output).
// ---------------------------------------------------------------------------
__global__ __launch_bounds__(256, 4) void node_out(
    const short* __restrict__ scaled_b, const short* __restrict__ edge2r,
    const int4* __restrict__ nbr,
    const short8* __restrict__ bWq, const float* __restrict__ bq,
    float* __restrict__ out)
{
    __shared__ short s_t[16][72];    // tsum bf16; pad 64->72: frag rows 4 banks apart
    __shared__ float s_s[16][132];   // edge2 sums fp32; pad 128->132

    const int t = threadIdx.x;
    const int w = t >> 6, l = t & 63;
    const int lm = l & 15, lq = l >> 4;
    const int c = 2 * l;
    const int nbase = blockIdx.x * 16;

    #pragma unroll
    for (int j = 0; j < 4; ++j) {
        const int n = nbase + w * 4 + j;
        int4 nb[8];
        #pragma unroll
        for (int d = 0; d < 8; ++d) nb[d] = nbr[(size_t)n * 8 + d];

        float tsum = 0.f, s0 = 0.f, s1 = 0.f;
        #pragma unroll
        for (int d = 0; d < 8; ++d) {
            float g1 = bf2f(scaled_b[(size_t)nb[d].x * RANK + l]);
            float g2 = bf2f(scaled_b[(size_t)nb[d].y * RANK + l]);
            float g3 = bf2f(scaled_b[(size_t)nb[d].z * RANK + l]);
            short2v u = *reinterpret_cast<const short2v*>(edge2r + (size_t)nb[d].w * OUTD + c);
            tsum += fast_tanh(COEF * (g1 * (g2 * g3)));
            s0 += bf2f(u[0]);
            s1 += bf2f(u[1]);
        }
        s_t[w * 4 + j][l] = f2bf(tsum);
        *reinterpret_cast<float2*>(&s_s[w * 4 + j][c]) = make_float2(s0, s1);
    }
    __syncthreads();

    // MFMA mat-vec: Q^T = Wq^T @ T^T ; wave w owns out cols [w*32, +32)
    float4v acc0 = {0.f, 0.f, 0.f, 0.f}, acc1 = {0.f, 0.f, 0.f, 0.f};
    #pragma unroll
    for (int kt = 0; kt < 2; ++kt) {
        short8 tf = *reinterpret_cast<const short8*>(&s_t[lm][kt * 32 + lq * 8]);
        short8 w0 = bWq[((w * 2 + 0) * 2 + kt) * 64 + l];
        short8 w1 = bWq[((w * 2 + 1) * 2 + kt) * 64 + l];
        acc0 = __builtin_amdgcn_mfma_f32_16x16x32_bf16(w0, tf, acc0, 0, 0, 0);
        acc1 = __builtin_amdgcn_mfma_f32_16x16x32_bf16(w1, tf, acc1, 0, 0, 0);
    }
    #pragma unroll
    for (int n2 = 0; n2 < 2; ++n2) {
        float4v a = n2 ? acc1 : acc0;
        const int col = w * 32 + n2 * 16 + lq * 4;
        float4 sv = *reinterpret_cast<const float4*>(&s_s[lm][col]);
        float4 bb = *reinterpret_cast<const float4*>(bq + col);
        f32x4 o;
        o[0] = fmaxf(fmaf(0.125f, a[0] + sv.x, bb.x), 0.f);
        o[1] = fmaxf(fmaf(0.125f, a[1] + sv.y, bb.y), 0.f);
        o[2] = fmaxf(fmaf(0.125f, a[2] + sv.z, bb.z), 0.f);
        o[3] = fmaxf(fmaf(0.125f, a[3] + sv.w, bb.w), 0.f);
        __builtin_nontemporal_store(o, reinterpret_cast<f32x4*>(out + (size_t)(nbase + lm) * OUTD + col));
    }
}

extern "C" void kernel_launch(void* const* d_in, const int* in_sizes, int n_in,
                              void* d_out, int out_size, void* d_ws, size_t ws_size,
                              hipStream_t stream)
{
    const float* emb = (const float*)d_in[0];
    const float* Wp  = (const float*)d_in[1];
    const float* bp  = (const float*)d_in[2];
    const float* Wq  = (const float*)d_in[3];
    const float* bq  = (const float*)d_in[4];
    const float* W1  = (const float*)d_in[5];
    const float* b1  = (const float*)d_in[6];
    const float* W2  = (const float*)d_in[7];
    const float* b2  = (const float*)d_in[8];
    const int* edge_nodes = (const int*)d_in[9];
    float* out = (float*)d_out;

    // workspace layout (r0); nbr ALIASES emb2_b (emb2_b dead after edge_sum).
    short* scaled_b = (short*)d_ws;                          // NN*64  bf16 = 12.8 MB
    short* emb2_b   = scaled_b + (size_t)NN * RANK;          // NN*128 bf16 = 25.6 MB
    short* edge2r   = emb2_b + (size_t)NN * OUTD;            // EE*128 bf16 = 51.2 MB
    short* bWp      = edge2r + (size_t)EE * OUTD;            // 32 KB
    short* bW1      = bWp + 256 * 64;                        // 256 KB
    short* bW2      = bW1 + 256 * 512;                       // 128 KB
    short* bWq      = bW2 + 512 * 128;                       // 16 KB
    int4*  nbr      = (int4*)emb2_b;                         // NN*8 int4 = 12.8 MB (alias)

    pack_w<<<108, 256, 0, stream>>>(Wp, W1, W2, Wq, bWp, bW1, bW2, bWq);
    node_net_mfma<<<NN / 32, 256, 0, stream>>>(
        emb, (const short8*)bWp, bp, (const short8*)bW1, b1, (const short8*)bW2, b2,
        scaled_b, emb2_b);
    edge_sum<<<EE / 32, 256, 0, stream>>>(emb2_b, edge_nodes, edge2r);
    make_nbr<<<EE * KK / 256, 256, 0, stream>>>(edge_nodes, nbr);   // overwrites emb2_b
    node_out<<<NN / 16, 256, 0, stream>>>(scaled_b, edge2r, nbr, (const short8*)bWq, bq, out);
}

// Round 10
// 349.195 us; speedup vs baseline: 1.1110x; 1.0104x over previous
//
#include <hip/hip_runtime.h>
#include <hip/hip_bf16.h>
#include <math.h>

#define NN   100000
#define EE   200000
#define KK   4
#define DEG  8
#define FEAT 256
#define RANK 64
#define HID  512
#define OUTD 128
#define EPB  25000   // edges per permutation block = NN/KK

// num = DEG^(1/K) = 8^0.25 ; coef = num / (K-1)! = num/6
#define NUMF  1.6817928305074290861f
#define COEF  0.28029880508457151435f

typedef __attribute__((ext_vector_type(8))) short short8;
typedef __attribute__((ext_vector_type(4))) short short4v;
typedef __attribute__((ext_vector_type(2))) short short2v;
typedef __attribute__((ext_vector_type(4))) float float4v;
typedef __attribute__((ext_vector_type(4))) float f32x4;   // nt-capable 16B vector

__device__ __forceinline__ short f2bf(float x) {
    union { float f; unsigned u; } v; v.f = x;
    unsigned r = v.u + 0x7fff + ((v.u >> 16) & 1);   // RNE
    return (short)(r >> 16);
}
__device__ __forceinline__ float bf2f(short u) {
    union { unsigned u; float f; } v;
    v.u = ((unsigned)(unsigned short)u) << 16;
    return v.f;
}
// fast tanh: 1 - 2/(e^{2y}+1); exact at +-inf, ~1ulp of v_exp_f32 elsewhere
__device__ __forceinline__ float fast_tanh(float y) {
    float ez = __expf(2.f * y);
    return 1.f - 2.f * __builtin_amdgcn_rcpf(ez + 1.f);
}

// ---------------------------------------------------------------------------
// prep = pack_w + make_nbr fused (both depend only on kernel inputs; nbr is
// de-aliased from emb2_b to allow this). 5 launches -> 4: tests the ~14us/
// launch overhead hypothesis from the r9 budget audit.
// Blocks 0..107: pack Wp/W1/W2/Wq into bf16 MFMA B-fragment order.
// Blocks 108..3232: nbr[n*8+d] = {o0,o1,o2,e} (one writer per cell).
// ---------------------------------------------------------------------------
__global__ __launch_bounds__(256) void prep(
    const float* __restrict__ Wp, const float* __restrict__ W1,
    const float* __restrict__ W2, const float* __restrict__ Wq,
    short* __restrict__ bWp, short* __restrict__ bW1,
    short* __restrict__ bW2, short* __restrict__ bWq,
    const int* __restrict__ edge_nodes, int4* __restrict__ nbr)
{
    if (blockIdx.x < 108) {
        int g = blockIdx.x * 256 + threadIdx.x;   // 108 blocks * 256 = (32+256+128+16)*64
        int tile = g >> 6, l = g & 63;
        int lm = l & 15, lq = l >> 4;
        const float* src; short* dst; int N, kt, nt, tl;
        if (tile < 32)       { tl = tile;        nt = tl >> 3; kt = tl & 7;  src = Wp; dst = bWp; N = RANK; }
        else if (tile < 288) { tl = tile - 32;   nt = tl >> 3; kt = tl & 7;  src = W1; dst = bW1; N = HID;  }
        else if (tile < 416) { tl = tile - 288;  nt = tl >> 4; kt = tl & 15; src = W2; dst = bW2; N = OUTD; }
        else                 { tl = tile - 416;  nt = tl >> 1; kt = tl & 1;  src = Wq; dst = bWq; N = OUTD; }
        short8 pk;
        #pragma unroll
        for (int j = 0; j < 8; ++j)
            pk[j] = f2bf(src[(size_t)(kt * 32 + lq * 8 + j) * N + nt * 16 + lm]);
        *reinterpret_cast<short8*>(dst + (size_t)(tl * 64 + l) * 8) = pk;
    } else {
        int i = (blockIdx.x - 108) * 256 + threadIdx.x;   // < EE*KK = 800000
        int e = i >> 2, k = i & 3;
        const int4 nd = *reinterpret_cast<const int4*>(edge_nodes + (size_t)e * KK);
        int n  = (k == 0) ? nd.x : (k == 1) ? nd.y : (k == 2) ? nd.z : nd.w;
        int o0 = (k == 0) ? nd.y : nd.x;
        int o1 = (k <= 1) ? nd.z : nd.y;
        int o2 = (k <= 2) ? nd.w : nd.z;
        int d = e / EPB;
        nbr[(size_t)n * 8 + d] = make_int4(o0, o1, o2, e);
    }
}

// ---------------------------------------------------------------------------
// Fused node network (r0 structure, 32 rows/block — proven local optimum).
// emb loads NON-TEMPORAL (r8/r9: -11us, FETCH 54->51.8MB — emb is a zero-
// reuse 102MB stream; nt keeps L3 for the high-reuse gather intermediates).
// ---------------------------------------------------------------------------
__global__ __launch_bounds__(256) void node_net_mfma(
    const float* __restrict__ emb,
    const short8* __restrict__ bWp, const float* __restrict__ bp,
    const short8* __restrict__ bW1, const float* __restrict__ b1,
    const short8* __restrict__ bW2, const float* __restrict__ b2,
    short* __restrict__ scaled_b, short* __restrict__ emb2_b)
{
    __shared__ short s_a[32][264];   // 32 x 256 bf16, row stride 528 B
    __shared__ short s_h[32][136];   // 32 x 128 bf16 chunk

    const int t = threadIdx.x;
    const int w = t >> 6, l = t & 63;
    const int lm = l & 15, lq = l >> 4;
    const int row0 = blockIdx.x * 32;

    for (int i = t; i < 32 * 32; i += 256) {
        int r = i >> 5, c8 = (i & 31) * 8;
        const f32x4* src = reinterpret_cast<const f32x4*>(emb + (size_t)(row0 + r) * FEAT + c8);
        f32x4 v0 = __builtin_nontemporal_load(src);        // nt: keep L3 for intermediates
        f32x4 v1 = __builtin_nontemporal_load(src + 1);
        short8 pk;
        pk[0] = f2bf(v0[0]); pk[1] = f2bf(v0[1]); pk[2] = f2bf(v0[2]); pk[3] = f2bf(v0[3]);
        pk[4] = f2bf(v1[0]); pk[5] = f2bf(v1[1]); pk[6] = f2bf(v1[2]); pk[7] = f2bf(v1[3]);
        *reinterpret_cast<short8*>(&s_a[r][c8]) = pk;
    }
    __syncthreads();

    // ---- stage p: scaled ----
    {
        float4v acc0 = {0.f, 0.f, 0.f, 0.f}, acc1 = {0.f, 0.f, 0.f, 0.f};
        #pragma unroll
        for (int kt = 0; kt < 8; ++kt) {
            short8 e0 = *reinterpret_cast<const short8*>(&s_a[lm][kt * 32 + lq * 8]);
            short8 e1 = *reinterpret_cast<const short8*>(&s_a[16 + lm][kt * 32 + lq * 8]);
            short8 wv = bWp[(w * 8 + kt) * 64 + l];
            acc0 = __builtin_amdgcn_mfma_f32_16x16x32_bf16(wv, e0, acc0, 0, 0, 0);
            acc1 = __builtin_amdgcn_mfma_f32_16x16x32_bf16(wv, e1, acc1, 0, 0, 0);
        }
        const int cb = w * 16 + lq * 4;
        float4 bb = *reinterpret_cast<const float4*>(bp + cb);
        short4v o0 = { f2bf(NUMF * (acc0[0] + bb.x)), f2bf(NUMF * (acc0[1] + bb.y)),
                       f2bf(NUMF * (acc0[2] + bb.z)), f2bf(NUMF * (acc0[3] + bb.w)) };
        short4v o1 = { f2bf(NUMF * (acc1[0] + bb.x)), f2bf(NUMF * (acc1[1] + bb.y)),
                       f2bf(NUMF * (acc1[2] + bb.z)), f2bf(NUMF * (acc1[3] + bb.w)) };
        *reinterpret_cast<short4v*>(scaled_b + (size_t)(row0 + lm) * RANK + cb)      = o0;
        *reinterpret_cast<short4v*>(scaled_b + (size_t)(row0 + 16 + lm) * RANK + cb) = o1;
    }

    // ---- chunk-fused stage1/stage2 ----
    float4v eacc[2][2];
    #pragma unroll
    for (int mt = 0; mt < 2; ++mt)
        #pragma unroll
        for (int n2 = 0; n2 < 2; ++n2)
            eacc[mt][n2] = (float4v){0.f, 0.f, 0.f, 0.f};

    for (int cc = 0; cc < 4; ++cc) {
        #pragma unroll
        for (int nt2 = 0; nt2 < 2; ++nt2) {
            float4v h0 = {0.f, 0.f, 0.f, 0.f}, h1 = {0.f, 0.f, 0.f, 0.f};
            const int gnt = cc * 8 + w * 2 + nt2;
            #pragma unroll
            for (int kt = 0; kt < 8; ++kt) {
                short8 e0 = *reinterpret_cast<const short8*>(&s_a[lm][kt * 32 + lq * 8]);
                short8 e1 = *reinterpret_cast<const short8*>(&s_a[16 + lm][kt * 32 + lq * 8]);
                short8 wv = bW1[(gnt * 8 + kt) * 64 + l];
                h0 = __builtin_amdgcn_mfma_f32_16x16x32_bf16(wv, e0, h0, 0, 0, 0);
                h1 = __builtin_amdgcn_mfma_f32_16x16x32_bf16(wv, e1, h1, 0, 0, 0);
            }
            const int col  = w * 32 + nt2 * 16 + lq * 4;   // chunk-local
            float4 bb = *reinterpret_cast<const float4*>(b1 + cc * 128 + col);
            short4v o0 = { f2bf(fmaxf(h0[0] + bb.x, 0.f)), f2bf(fmaxf(h0[1] + bb.y, 0.f)),
                           f2bf(fmaxf(h0[2] + bb.z, 0.f)), f2bf(fmaxf(h0[3] + bb.w, 0.f)) };
            short4v o1 = { f2bf(fmaxf(h1[0] + bb.x, 0.f)), f2bf(fmaxf(h1[1] + bb.y, 0.f)),
                           f2bf(fmaxf(h1[2] + bb.z, 0.f)), f2bf(fmaxf(h1[3] + bb.w, 0.f)) };
            *reinterpret_cast<short4v*>(&s_h[lm][col])      = o0;
            *reinterpret_cast<short4v*>(&s_h[16 + lm][col]) = o1;
        }
        __syncthreads();

        #pragma unroll
        for (int kt2 = 0; kt2 < 4; ++kt2) {
            short8 hh0 = *reinterpret_cast<const short8*>(&s_h[lm][kt2 * 32 + lq * 8]);
            short8 hh1 = *reinterpret_cast<const short8*>(&s_h[16 + lm][kt2 * 32 + lq * 8]);
            const int gk = cc * 4 + kt2;
            #pragma unroll
            for (int n2 = 0; n2 < 2; ++n2) {
                short8 wv = bW2[((w * 2 + n2) * 16 + gk) * 64 + l];
                eacc[0][n2] = __builtin_amdgcn_mfma_f32_16x16x32_bf16(wv, hh0, eacc[0][n2], 0, 0, 0);
                eacc[1][n2] = __builtin_amdgcn_mfma_f32_16x16x32_bf16(wv, hh1, eacc[1][n2], 0, 0, 0);
            }
        }
        __syncthreads();
    }

    #pragma unroll
    for (int n2 = 0; n2 < 2; ++n2) {
        const int col = w * 32 + n2 * 16 + lq * 4;
        float4 bb = *reinterpret_cast<const float4*>(b2 + col);
        #pragma unroll
        for (int mt = 0; mt < 2; ++mt) {
            short4v o = { f2bf(eacc[mt][n2][0] + bb.x), f2bf(eacc[mt][n2][1] + bb.y),
                          f2bf(eacc[mt][n2][2] + bb.z), f2bf(eacc[mt][n2][3] + bb.w) };
            *reinterpret_cast<short4v*>(emb2_b + (size_t)(row0 + mt * 16 + lm) * OUTD + col) = o;
        }
    }
}

// ---------------------------------------------------------------------------
// Per-edge: edge2r = bf16( relu( sum_k emb2[node_k] ) ).
// emb2_b rows have 8x reuse across edges -> keep cached (no nt).
// ---------------------------------------------------------------------------
__global__ __launch_bounds__(256) void edge_sum(
    const short* __restrict__ emb2_b, const int* __restrict__ edge_nodes,
    short* __restrict__ edge2r)
{
    const int t = threadIdx.x;
    const int w = t >> 6, l = t & 63;
    const int c = 2 * l;
    const int e0 = blockIdx.x * 32 + w * 8;
    #pragma unroll
    for (int it = 0; it < 8; ++it) {
        const int e = e0 + it;
        const int4 nd = *reinterpret_cast<const int4*>(edge_nodes + (size_t)e * KK);
        short2v u0 = *reinterpret_cast<const short2v*>(emb2_b + (size_t)nd.x * OUTD + c);
        short2v u1 = *reinterpret_cast<const short2v*>(emb2_b + (size_t)nd.y * OUTD + c);
        short2v u2 = *reinterpret_cast<const short2v*>(emb2_b + (size_t)nd.z * OUTD + c);
        short2v u3 = *reinterpret_cast<const short2v*>(emb2_b + (size_t)nd.w * OUTD + c);
        float s0 = bf2f(u0[0]) + bf2f(u1[0]) + bf2f(u2[0]) + bf2f(u3[0]);
        float s1 = bf2f(u0[1]) + bf2f(u1[1]) + bf2f(u2[1]) + bf2f(u3[1]);
        short2v o = { f2bf(fmaxf(s0, 0.f)), f2bf(fmaxf(s1, 0.f)) };
        *reinterpret_cast<short2v*>(edge2r + (size_t)e * OUTD + c) = o;
    }
}

// ---------------------------------------------------------------------------
// Per-node (r0 structure): 16 nodes/block, 4 nodes/wave gather phase, then
// one swapped-operand Wq MFMA (lane=node C-layout) + fused epilogue.
// scaled_b/edge2r/nbr: cached (high reuse / address-feeding; r8 lesson:
// never nt a load that feeds addresses). out: nt store (write-once stream).
// ---------------------------------------------------------------------------
__global__ __launch_bounds__(256, 4) void node_out(
    const short* __restrict__ scaled_b, const short* __restrict__ edge2r,
    const int4* __restrict__ nbr,
    const short8* __restrict__ bWq, const float* __restrict__ bq,
    float* __restrict__ out)
{
    __shared__ short s_t[16][72];    // tsum bf16; pad 64->72: frag rows 4 banks apart
    __shared__ float s_s[16][132];   // edge2 sums fp32; pad 128->132

    const int t = threadIdx.x;
    const int w = t >> 6, l = t & 63;
    const int lm = l & 15, lq = l >> 4;
    const int c = 2 * l;
    const int nbase = blockIdx.x * 16;

    #pragma unroll
    for (int j = 0; j < 4; ++j) {
        const int n = nbase + w * 4 + j;
        int4 nb[8];
        #pragma unroll
        for (int d = 0; d < 8; ++d) nb[d] = nbr[(size_t)n * 8 + d];

        float tsum = 0.f, s0 = 0.f, s1 = 0.f;
        #pragma unroll
        for (int d = 0; d < 8; ++d) {
            float g1 = bf2f(scaled_b[(size_t)nb[d].x * RANK + l]);
            float g2 = bf2f(scaled_b[(size_t)nb[d].y * RANK + l]);
            float g3 = bf2f(scaled_b[(size_t)nb[d].z * RANK + l]);
            short2v u = *reinterpret_cast<const short2v*>(edge2r + (size_t)nb[d].w * OUTD + c);
            tsum += fast_tanh(COEF * (g1 * (g2 * g3)));
            s0 += bf2f(u[0]);
            s1 += bf2f(u[1]);
        }
        s_t[w * 4 + j][l] = f2bf(tsum);
        *reinterpret_cast<float2*>(&s_s[w * 4 + j][c]) = make_float2(s0, s1);
    }
    __syncthreads();

    // MFMA mat-vec: Q^T = Wq^T @ T^T ; wave w owns out cols [w*32, +32)
    float4v acc0 = {0.f, 0.f, 0.f, 0.f}, acc1 = {0.f, 0.f, 0.f, 0.f};
    #pragma unroll
    for (int kt = 0; kt < 2; ++kt) {
        short8 tf = *reinterpret_cast<const short8*>(&s_t[lm][kt * 32 + lq * 8]);
        short8 w0 = bWq[((w * 2 + 0) * 2 + kt) * 64 + l];
        short8 w1 = bWq[((w * 2 + 1) * 2 + kt) * 64 + l];
        acc0 = __builtin_amdgcn_mfma_f32_16x16x32_bf16(w0, tf, acc0, 0, 0, 0);
        acc1 = __builtin_amdgcn_mfma_f32_16x16x32_bf16(w1, tf, acc1, 0, 0, 0);
    }
    #pragma unroll
    for (int n2 = 0; n2 < 2; ++n2) {
        float4v a = n2 ? acc1 : acc0;
        const int col = w * 32 + n2 * 16 + lq * 4;
        float4 sv = *reinterpret_cast<const float4*>(&s_s[lm][col]);
        float4 bb = *reinterpret_cast<const float4*>(bq + col);
        f32x4 o;
        o[0] = fmaxf(fmaf(0.125f, a[0] + sv.x, bb.x), 0.f);
        o[1] = fmaxf(fmaf(0.125f, a[1] + sv.y, bb.y), 0.f);
        o[2] = fmaxf(fmaf(0.125f, a[2] + sv.z, bb.z), 0.f);
        o[3] = fmaxf(fmaf(0.125f, a[3] + sv.w, bb.w), 0.f);
        __builtin_nontemporal_store(o, reinterpret_cast<f32x4*>(out + (size_t)(nbase + lm) * OUTD + col));
    }
}

extern "C" void kernel_launch(void* const* d_in, const int* in_sizes, int n_in,
                              void* d_out, int out_size, void* d_ws, size_t ws_size,
                              hipStream_t stream)
{
    const float* emb = (const float*)d_in[0];
    const float* Wp  = (const float*)d_in[1];
    const float* bp  = (const float*)d_in[2];
    const float* Wq  = (const float*)d_in[3];
    const float* bq  = (const float*)d_in[4];
    const float* W1  = (const float*)d_in[5];
    const float* b1  = (const float*)d_in[6];
    const float* W2  = (const float*)d_in[7];
    const float* b2  = (const float*)d_in[8];
    const int* edge_nodes = (const int*)d_in[9];
    float* out = (float*)d_out;

    // workspace layout: nbr now DE-ALIASED (own region) so prep can write it
    // up-front. Total ~103 MB (r3's 167 MB path ran, so ws_size is ample).
    short* scaled_b = (short*)d_ws;                          // NN*64  bf16 = 12.8 MB
    short* emb2_b   = scaled_b + (size_t)NN * RANK;          // NN*128 bf16 = 25.6 MB
    short* edge2r   = emb2_b + (size_t)NN * OUTD;            // EE*128 bf16 = 51.2 MB
    short* bWp      = edge2r + (size_t)EE * OUTD;            // 32 KB
    short* bW1      = bWp + 256 * 64;                        // 256 KB
    short* bW2      = bW1 + 256 * 512;                       // 128 KB
    short* bWq      = bW2 + 512 * 128;                       // 16 KB
    int4*  nbr      = (int4*)(bWq + 64 * 128);               // NN*8 int4 = 12.8 MB

    prep<<<108 + EE * KK / 256, 256, 0, stream>>>(
        Wp, W1, W2, Wq, bWp, bW1, bW2, bWq, edge_nodes, nbr);
    node_net_mfma<<<NN / 32, 256, 0, stream>>>(
        emb, (const short8*)bWp, bp, (const short8*)bW1, b1, (const short8*)bW2, b2,
        scaled_b, emb2_b);
    edge_sum<<<EE / 32, 256, 0, stream>>>(emb2_b, edge_nodes, edge2r);
    node_out<<<NN / 16, 256, 0, stream>>>(scaled_b, edge2r, nbr, (const short8*)bWq, bq, out);
}